// Round 4
// baseline (189.145 us; speedup 1.0000x reference)
//
#include <hip/hip_runtime.h>
#include <hip/hip_bf16.h>

typedef short short8 __attribute__((ext_vector_type(8)));
typedef short short4v __attribute__((ext_vector_type(4)));
typedef float f32x4 __attribute__((ext_vector_type(4)));
typedef unsigned short ushort_t;

// ---------- bf16 helpers ----------
__device__ inline ushort_t f2bf(float f) {            // manual RNE (cold paths)
    union { float f; unsigned u; } x; x.f = f;
    unsigned r = x.u + 0x7fffu + ((x.u >> 16) & 1u);
    return (ushort_t)(r >> 16);
}
__device__ inline ushort_t f2bf_u(float x) {           // toolchain conversion (hot paths)
    union { __hip_bfloat16 h; ushort_t u; } cv;
    cv.h = __float2bfloat16(x);
    return cv.u;
}
__device__ inline float bf2f(ushort_t u) {
    union { unsigned u; float f; } cv; cv.u = ((unsigned)u) << 16; return cv.f;
}

// ---------- transpose + convert weights: Wt[j][k] = bf16(W[k][j]), K=256 rows ----------
__global__ __launch_bounds__(256) void prep_w_kernel(const float* __restrict__ w0,
                                                     const float* __restrict__ w1,
                                                     const float* __restrict__ w2,
                                                     const float* __restrict__ w3,
                                                     ushort_t* __restrict__ t0,
                                                     ushort_t* __restrict__ t1,
                                                     ushort_t* __restrict__ t2,
                                                     ushort_t* __restrict__ t3) {
    int z = blockIdx.y;
    const float* W; ushort_t* T; int J;
    if (z == 0)      { W = w0; T = t0; J = 512; }
    else if (z == 1) { W = w1; T = t1; J = 512; }
    else if (z == 2) { W = w2; T = t2; J = 256; }
    else             { W = w3; T = t3; J = 256; }
    int idx = blockIdx.x * 256 + threadIdx.x;   // idx = j*256 + k
    if (idx >= J * 256) return;
    int k = idx & 255, j = idx >> 8;
    T[idx] = f2bf(W[k * J + j]);
}

// ---------- in-projection GEMM (fused f32->bf16 convert of A) ----------
__global__ __launch_bounds__(256) void gemm_in_kernel(
    const float* __restrict__ A0, const float* __restrict__ A1,
    const ushort_t* __restrict__ B0, const ushort_t* __restrict__ B1,
    ushort_t* __restrict__ R0, ushort_t* __restrict__ R1,
    ushort_t* __restrict__ V0, ushort_t* __restrict__ V1) {
    const float* A = blockIdx.z ? A1 : A0;
    const ushort_t* Bt = blockIdx.z ? B1 : B0;
    ushort_t* R = blockIdx.z ? R1 : R0;
    ushort_t* Vt = blockIdx.z ? V1 : V0;
    constexpr int K = 256;
    const int w = threadIdx.x >> 6, lane = threadIdx.x & 63;
    const int l16 = lane & 15, g = lane >> 4;
    const int m0 = blockIdx.x * 64 + w * 16;
    const int cb = blockIdx.y * 64;

    f32x4 acc[4] = {};
    const float* Ap = A + (size_t)(m0 + l16) * K + 8 * g;
    const ushort_t* Bp = Bt + (size_t)(cb + l16) * K + 8 * g;

    #pragma unroll
    for (int ks = 0; ks < K; ks += 32) {
        float4 af0 = *reinterpret_cast<const float4*>(Ap + ks);
        float4 af1 = *reinterpret_cast<const float4*>(Ap + ks + 4);
        short8 a;
        a[0] = (short)f2bf_u(af0.x); a[1] = (short)f2bf_u(af0.y);
        a[2] = (short)f2bf_u(af0.z); a[3] = (short)f2bf_u(af0.w);
        a[4] = (short)f2bf_u(af1.x); a[5] = (short)f2bf_u(af1.y);
        a[6] = (short)f2bf_u(af1.z); a[7] = (short)f2bf_u(af1.w);
        #pragma unroll
        for (int c = 0; c < 4; ++c) {
            short8 b = *reinterpret_cast<const short8*>(Bp + (size_t)c * 16 * K + ks);
            acc[c] = __builtin_amdgcn_mfma_f32_16x16x32_bf16(a, b, acc[c], 0, 0, 0);
        }
    }

    if (blockIdx.y < 4) {
        #pragma unroll
        for (int c = 0; c < 4; ++c) {
            int col = cb + c * 16 + l16;        // 0..255
            int h = col >> 5, d = col & 31;
            #pragma unroll
            for (int r = 0; r < 4; ++r) {
                int row = m0 + 4 * g + r;
                int bb = row >> 11, n = row & 2047;
                R[((size_t)(bb * 8 + h) * 2048 + n) * 32 + d] = f2bf_u(acc[c][r]);
            }
        }
    } else {
        #pragma unroll
        for (int c = 0; c < 4; ++c) {
            int colp = cb - 256 + c * 16 + l16; // 0..255
            int h = colp >> 5, d = colp & 31;
            int row = m0 + 4 * g;
            int bb = row >> 11, n = row & 2047;
            ushort4 s;
            s.x = f2bf_u(acc[c][0]); s.y = f2bf_u(acc[c][1]);
            s.z = f2bf_u(acc[c][2]); s.w = f2bf_u(acc[c][3]);
            *reinterpret_cast<ushort4*>(Vt + ((size_t)(bb * 8 + h) * 32 + d) * 2048 + n) = s;
        }
    }
}

// ---------- flash attention, both directions, no LDS ----------
// rH: [16][2048][32] bf16. vT: [16][32][2048] bf16. O: [B][N][256] bf16.
// 1024 blocks, XCD-swizzled (4 streams per XCD => 1 MB L2 working set/XCD).
// Each wave: 16 q-rows, depth-2 register prefetch (4 tile buffers, unroll 4),
// deferred-max online softmax, no LDS / no barriers.
__global__ __launch_bounds__(256, 4) void attn_kernel(
    const ushort_t* __restrict__ r_sed, const ushort_t* __restrict__ r_doa,
    const ushort_t* __restrict__ vT_sed, const ushort_t* __restrict__ vT_doa,
    ushort_t* __restrict__ o_sed, ushort_t* __restrict__ o_doa) {
    const int flat = blockIdx.x;           // 0..1023
    const int xcd = flat & 7;
    const int ii = flat >> 3;              // 0..127
    const int yz = xcd * 4 + (ii & 3);     // 0..31: (dir,bh) stream id
    const int xb = ii >> 2;                // 0..31: q-tile
    const int dir = yz >> 4;
    const int bh = yz & 15;
    const int b = bh >> 3, h = bh & 7;

    const ushort_t* rQ = dir ? r_doa : r_sed;
    const ushort_t* rK = dir ? r_sed : r_doa;
    const ushort_t* vT = dir ? vT_sed : vT_doa;
    ushort_t* O = dir ? o_doa : o_sed;

    const int w = threadIdx.x >> 6;
    const int lane = threadIdx.x & 63;
    const int l16 = lane & 15, g = lane >> 4;
    const int q_row = xb * 64 + w * 16 + l16;

    // Q fragment, pre-scaled by SCALE*log2(e)
    const float C2 = 0.17677669529663687f * 1.4426950408889634f;
    short8 qf;
    {
        short8 q0 = *reinterpret_cast<const short8*>(rQ + ((size_t)bh * 2048 + q_row) * 32 + 8 * g);
        #pragma unroll
        for (int i = 0; i < 8; ++i) qf[i] = (short)f2bf(bf2f((ushort_t)q0[i]) * C2);
    }

    const ushort_t* Kb = rK + (size_t)bh * 2048 * 32 + 8 * g;
    const ushort_t* Vp0 = vT + ((size_t)bh * 32 + l16) * 2048 + 4 * g;   // d = l16
    const ushort_t* Vp1 = Vp0 + (size_t)16 * 2048;                       // d = l16+16

    float m = -1e30f, m8 = -1e30f;
    f32x4 lv = {};
    f32x4 acc0 = {}, acc1 = {};

    #define LOADT(T, K0, K1, V0_, V1_) do {                                          \
        int kv0 = (T) * 32;                                                          \
        K0 = *reinterpret_cast<const short8*>(Kb + (size_t)(kv0 + l16) * 32);        \
        K1 = *reinterpret_cast<const short8*>(Kb + (size_t)(kv0 + 16 + l16) * 32);   \
        short4v t0 = *reinterpret_cast<const short4v*>(Vp0 + kv0);                   \
        short4v t1 = *reinterpret_cast<const short4v*>(Vp0 + kv0 + 16);              \
        short4v t2 = *reinterpret_cast<const short4v*>(Vp1 + kv0);                   \
        short4v t3 = *reinterpret_cast<const short4v*>(Vp1 + kv0 + 16);              \
        V0_ = __builtin_shufflevector(t0, t1, 0, 1, 2, 3, 4, 5, 6, 7);               \
        V1_ = __builtin_shufflevector(t2, t3, 0, 1, 2, 3, 4, 5, 6, 7);               \
    } while (0)

    auto step = [&](short8 kf0, short8 kf1, short8 vf0, short8 vf1) {
        const f32x4 z4 = {};
        f32x4 st0 = __builtin_amdgcn_mfma_f32_16x16x32_bf16(kf0, qf, z4, 0, 0, 0);
        f32x4 st1 = __builtin_amdgcn_mfma_f32_16x16x32_bf16(kf1, qf, z4, 0, 0, 0);

        float pmax = fmaxf(fmaxf(fmaxf(st0[0], st0[1]), fmaxf(st0[2], st0[3])),
                           fmaxf(fmaxf(st1[0], st1[1]), fmaxf(st1[2], st1[3])));

        if (!__all(pmax <= m8)) {                 // deferred-max trigger (rare)
            float pm = fmaxf(pmax, __shfl_xor(pmax, 16));
            pm = fmaxf(pm, __shfl_xor(pm, 32));
            float mn = fmaxf(m, pm);
            float alpha = __builtin_amdgcn_exp2f(m - mn);
            lv *= alpha; acc0 *= alpha; acc1 *= alpha;
            m = mn; m8 = mn + 8.0f;
        }

        f32x4 p0, p1;
        #pragma unroll
        for (int r = 0; r < 4; ++r) {
            p0[r] = __builtin_amdgcn_exp2f(st0[r] - m);
            p1[r] = __builtin_amdgcn_exp2f(st1[r] - m);
        }
        lv += p0; lv += p1;

        short8 pf;
        #pragma unroll
        for (int r = 0; r < 4; ++r) {
            pf[r] = (short)f2bf_u(p0[r]); pf[4 + r] = (short)f2bf_u(p1[r]);
        }

        acc0 = __builtin_amdgcn_mfma_f32_16x16x32_bf16(vf0, pf, acc0, 0, 0, 0);
        acc1 = __builtin_amdgcn_mfma_f32_16x16x32_bf16(vf1, pf, acc1, 0, 0, 0);
    };

    // 64 tiles of 32 kv; 4 statically-named buffers, depth-2 lookahead.
    short8 kA0, kA1, vA0, vA1, kB0, kB1, vB0, vB1;
    short8 kC0, kC1, vC0, vC1, kD0, kD1, vD0, vD1;
    LOADT(0, kA0, kA1, vA0, vA1);
    LOADT(1, kB0, kB1, vB0, vB1);
    for (int t = 0; t < 64; t += 4) {
        LOADT(t + 2, kC0, kC1, vC0, vC1);
        step(kA0, kA1, vA0, vA1);
        LOADT(t + 3, kD0, kD1, vD0, vD1);
        step(kB0, kB1, vB0, vB1);
        if (t + 4 < 64) LOADT(t + 4, kA0, kA1, vA0, vA1);
        step(kC0, kC1, vC0, vC1);
        if (t + 5 < 64) LOADT(t + 5, kB0, kB1, vB0, vB1);
        step(kD0, kD1, vD0, vD1);
    }
    #undef LOADT

    float l = (lv[0] + lv[1]) + (lv[2] + lv[3]);
    l += __shfl_xor(l, 16);
    l += __shfl_xor(l, 32);
    const float inv = 1.0f / l;

    ushort_t* orow = O + ((size_t)b * 2048 + q_row) * 256 + h * 32;
    ushort4 o0, o1;
    o0.x = f2bf(acc0[0] * inv); o0.y = f2bf(acc0[1] * inv);
    o0.z = f2bf(acc0[2] * inv); o0.w = f2bf(acc0[3] * inv);
    o1.x = f2bf(acc1[0] * inv); o1.y = f2bf(acc1[1] * inv);
    o1.z = f2bf(acc1[2] * inv); o1.w = f2bf(acc1[3] * inv);
    *reinterpret_cast<ushort4*>(orow + 4 * g) = o0;
    *reinterpret_cast<ushort4*>(orow + 16 + 4 * g) = o1;
}

// ---------- out-projection GEMM: C[4096 x 256] = A @ Bt^T + bias, f32 out ----------
__global__ __launch_bounds__(256) void gemm_out_kernel(
    const ushort_t* __restrict__ a0, const ushort_t* __restrict__ a1,
    const ushort_t* __restrict__ b0, const ushort_t* __restrict__ b1,
    float* __restrict__ c0, float* __restrict__ c1,
    const float* __restrict__ bias0, const float* __restrict__ bias1) {
    const ushort_t* A = blockIdx.z ? a1 : a0;
    const ushort_t* Bt = blockIdx.z ? b1 : b0;
    float* C = blockIdx.z ? c1 : c0;
    const float* bias = blockIdx.z ? bias1 : bias0;
    constexpr int K = 256, N = 256;
    const int w = threadIdx.x >> 6, lane = threadIdx.x & 63;
    const int l16 = lane & 15, g = lane >> 4;
    const int m0 = blockIdx.x * 64 + w * 16;
    const int cb = blockIdx.y * 64;

    f32x4 acc[4] = {};
    const ushort_t* Ap = A + (size_t)(m0 + l16) * K + 8 * g;
    const ushort_t* Bp = Bt + (size_t)(cb + l16) * K + 8 * g;
    #pragma unroll
    for (int ks = 0; ks < K; ks += 32) {
        short8 a = *reinterpret_cast<const short8*>(Ap + ks);
        #pragma unroll
        for (int c = 0; c < 4; ++c) {
            short8 b = *reinterpret_cast<const short8*>(Bp + (size_t)c * 16 * K + ks);
            acc[c] = __builtin_amdgcn_mfma_f32_16x16x32_bf16(a, b, acc[c], 0, 0, 0);
        }
    }
    #pragma unroll
    for (int c = 0; c < 4; ++c) {
        int col = cb + c * 16 + l16;
        #pragma unroll
        for (int r = 0; r < 4; ++r) {
            int row = m0 + 4 * g + r;
            C[(size_t)row * N + col] = acc[c][r] + bias[col];
        }
    }
}

// ---------- launch ----------
extern "C" void kernel_launch(void* const* d_in, const int* in_sizes, int n_in,
                              void* d_out, int out_size, void* d_ws, size_t ws_size,
                              hipStream_t stream) {
    const float* x_sed     = (const float*)d_in[0];
    const float* x_doa     = (const float*)d_in[1];
    const float* W_sed_in  = (const float*)d_in[2];
    const float* W_doa_in  = (const float*)d_in[3];
    const float* W_sed_out = (const float*)d_in[4];
    const float* b_sed_out = (const float*)d_in[5];
    const float* W_doa_out = (const float*)d_in[6];
    const float* b_doa_out = (const float*)d_in[7];
    float* out = (float*)d_out;

    ushort_t* ws = (ushort_t*)d_ws;
    ushort_t* wt_si  = ws;                          // 512*256
    ushort_t* wt_di  = wt_si  + 131072;             // 512*256
    ushort_t* wt_so  = wt_di  + 131072;             // 256*256
    ushort_t* wt_do  = wt_so  + 65536;              // 256*256
    ushort_t* rH_sed = wt_do  + 65536;              // 16*2048*32
    ushort_t* rH_doa = rH_sed + 1048576;
    ushort_t* vT_sed = rH_doa + 1048576;            // 16*32*2048
    ushort_t* vT_doa = vT_sed + 1048576;
    ushort_t* o_sed  = vT_doa + 1048576;            // 4096*256
    ushort_t* o_doa  = o_sed  + 1048576;
    // total ~13.3 MB of ws

    prep_w_kernel<<<dim3(512, 4), 256, 0, stream>>>(W_sed_in, W_doa_in, W_sed_out, W_doa_out,
                                                    wt_si, wt_di, wt_so, wt_do);
    gemm_in_kernel<<<dim3(64, 8, 2), 256, 0, stream>>>(x_sed, x_doa, wt_si, wt_di,
                                                       rH_sed, rH_doa, vT_sed, vT_doa);
    attn_kernel<<<dim3(1024), 256, 0, stream>>>(rH_sed, rH_doa, vT_sed, vT_doa, o_sed, o_doa);
    gemm_out_kernel<<<dim3(64, 4, 2), 256, 0, stream>>>(o_sed, o_doa, wt_so, wt_do,
                                                        out, out + 1048576, b_sed_out, b_doa_out);
}

// Round 5
// 81.329 us; speedup vs baseline: 2.3257x; 2.3257x over previous
//
#include <hip/hip_runtime.h>
#include <hip/hip_bf16.h>

typedef short short8 __attribute__((ext_vector_type(8)));
typedef float f32x4 __attribute__((ext_vector_type(4)));
typedef unsigned short ushort_t;

// ---------- bf16 helpers ----------
__device__ inline ushort_t f2bf(float f) {            // manual RNE (cold paths)
    union { float f; unsigned u; } x; x.f = f;
    unsigned r = x.u + 0x7fffu + ((x.u >> 16) & 1u);
    return (ushort_t)(r >> 16);
}
__device__ inline ushort_t f2bf_u(float x) {           // toolchain conversion (hot paths)
    union { __hip_bfloat16 h; ushort_t u; } cv;
    cv.h = __float2bfloat16(x);
    return cv.u;
}
__device__ inline float bf2f(ushort_t u) {
    union { unsigned u; float f; } cv; cv.u = ((unsigned)u) << 16; return cv.f;
}

#define GLD_LDS16(src, dst)                                                  \
    __builtin_amdgcn_global_load_lds(                                        \
        (const __attribute__((address_space(1))) void*)(src),                \
        (__attribute__((address_space(3))) void*)(dst), 16, 0, 0)

// ---------- transpose + convert weights: Wt[j][k] = bf16(W[k][j]), K=256 rows ----------
__global__ __launch_bounds__(256) void prep_w_kernel(const float* __restrict__ w0,
                                                     const float* __restrict__ w1,
                                                     const float* __restrict__ w2,
                                                     const float* __restrict__ w3,
                                                     ushort_t* __restrict__ t0,
                                                     ushort_t* __restrict__ t1,
                                                     ushort_t* __restrict__ t2,
                                                     ushort_t* __restrict__ t3) {
    int z = blockIdx.y;
    const float* W; ushort_t* T; int J;
    if (z == 0)      { W = w0; T = t0; J = 512; }
    else if (z == 1) { W = w1; T = t1; J = 512; }
    else if (z == 2) { W = w2; T = t2; J = 256; }
    else             { W = w3; T = t3; J = 256; }
    int idx = blockIdx.x * 256 + threadIdx.x;   // idx = j*256 + k
    if (idx >= J * 256) return;
    int k = idx & 255, j = idx >> 8;
    T[idx] = f2bf(W[k * J + j]);
}

// ---------- in-projection GEMM (fused f32->bf16 convert of A) ----------
// Outputs: rH [16][2048][32] bf16 (head-major rows);
//          vP [16][32][2048] bf16, kv-permuted within each 32-group:
//          n' = (n&~31) + ((n>>2)&3)*8 + ((n>>4)&1)*4 + (n&3)
__global__ __launch_bounds__(256) void gemm_in_kernel(
    const float* __restrict__ A0, const float* __restrict__ A1,
    const ushort_t* __restrict__ B0, const ushort_t* __restrict__ B1,
    ushort_t* __restrict__ R0, ushort_t* __restrict__ R1,
    ushort_t* __restrict__ V0, ushort_t* __restrict__ V1) {
    const float* A = blockIdx.z ? A1 : A0;
    const ushort_t* Bt = blockIdx.z ? B1 : B0;
    ushort_t* R = blockIdx.z ? R1 : R0;
    ushort_t* Vt = blockIdx.z ? V1 : V0;
    constexpr int K = 256;
    const int w = threadIdx.x >> 6, lane = threadIdx.x & 63;
    const int l16 = lane & 15, g = lane >> 4;
    const int m0 = blockIdx.x * 64 + w * 16;
    const int cb = blockIdx.y * 64;

    f32x4 acc[4] = {};
    const float* Ap = A + (size_t)(m0 + l16) * K + 8 * g;
    const ushort_t* Bp = Bt + (size_t)(cb + l16) * K + 8 * g;

    #pragma unroll
    for (int ks = 0; ks < K; ks += 32) {
        float4 af0 = *reinterpret_cast<const float4*>(Ap + ks);
        float4 af1 = *reinterpret_cast<const float4*>(Ap + ks + 4);
        short8 a;
        a[0] = (short)f2bf_u(af0.x); a[1] = (short)f2bf_u(af0.y);
        a[2] = (short)f2bf_u(af0.z); a[3] = (short)f2bf_u(af0.w);
        a[4] = (short)f2bf_u(af1.x); a[5] = (short)f2bf_u(af1.y);
        a[6] = (short)f2bf_u(af1.z); a[7] = (short)f2bf_u(af1.w);
        #pragma unroll
        for (int c = 0; c < 4; ++c) {
            short8 b = *reinterpret_cast<const short8*>(Bp + (size_t)c * 16 * K + ks);
            acc[c] = __builtin_amdgcn_mfma_f32_16x16x32_bf16(a, b, acc[c], 0, 0, 0);
        }
    }

    if (blockIdx.y < 4) {
        #pragma unroll
        for (int c = 0; c < 4; ++c) {
            int col = cb + c * 16 + l16;        // 0..255
            int h = col >> 5, d = col & 31;
            #pragma unroll
            for (int r = 0; r < 4; ++r) {
                int row = m0 + 4 * g + r;
                int bb = row >> 11, n = row & 2047;
                R[((size_t)(bb * 8 + h) * 2048 + n) * 32 + d] = f2bf_u(acc[c][r]);
            }
        }
    } else {
        #pragma unroll
        for (int c = 0; c < 4; ++c) {
            int colp = cb - 256 + c * 16 + l16; // 0..255
            int h = colp >> 5, d = colp & 31;
            int row = m0 + 4 * g;
            int bb = row >> 11, n = row & 2047;
            int np = (n & ~31) + ((n >> 2) & 3) * 8 + ((n >> 4) & 1) * 4;
            ushort4 s;
            s.x = f2bf_u(acc[c][0]); s.y = f2bf_u(acc[c][1]);
            s.z = f2bf_u(acc[c][2]); s.w = f2bf_u(acc[c][3]);
            *reinterpret_cast<ushort4*>(Vt + ((size_t)(bb * 8 + h) * 32 + d) * 2048 + np) = s;
        }
    }
}

// ---------- flash attention: 2-phase LDS-staged pipeline ----------
// 256 blocks (XCD-bijective), 8 waves/block = one (dir,bh) stream x 256 q-rows.
// Per 128-kv tile: stage K(8KB)+V(8KB) via global_load_lds (2 instrs/wave),
// double-buffered; 4 compute steps of 32 kv; one __syncthreads per tile.
// Both-sides XOR chunk swizzle so ds_read_b128 quarters are ~conflict-free.
__global__ __launch_bounds__(512, 2) void attn_kernel(
    const ushort_t* __restrict__ r_sed, const ushort_t* __restrict__ r_doa,
    const ushort_t* __restrict__ vP_sed, const ushort_t* __restrict__ vP_doa,
    ushort_t* __restrict__ o_sed, ushort_t* __restrict__ o_doa) {
    __shared__ __align__(16) ushort_t smem[16384];   // 32KB: [buf][K 4096 | V 4096]

    const int bid = blockIdx.x;                 // 0..255
    const int xcd = bid & 7, idx = bid >> 3;    // idx 0..31
    const int stream = xcd * 4 + (idx & 3);     // 0..31
    const int qblk = idx >> 2;                  // 0..7
    const int dir = stream >> 4;
    const int bh = stream & 15;
    const int b = bh >> 3, h = bh & 7;

    const ushort_t* rQ = dir ? r_doa : r_sed;
    const ushort_t* rK = dir ? r_sed : r_doa;
    const ushort_t* vP = dir ? vP_sed : vP_doa;
    ushort_t* O = dir ? o_doa : o_sed;

    const int tid = threadIdx.x;
    const int w = tid >> 6;
    const int lane = tid & 63;
    const int l16 = lane & 15, g = lane >> 4;
    const int qbase = qblk * 256 + w * 32;

    // Q fragments (rows qbase+l16, qbase+16+l16), pre-scaled by SCALE*log2(e)
    const float C2 = 0.17677669529663687f * 1.4426950408889634f;
    short8 qa, qb;
    {
        short8 q0 = *reinterpret_cast<const short8*>(rQ + ((size_t)bh * 2048 + qbase + l16) * 32 + 8 * g);
        short8 q1 = *reinterpret_cast<const short8*>(rQ + ((size_t)bh * 2048 + qbase + 16 + l16) * 32 + 8 * g);
        #pragma unroll
        for (int i = 0; i < 8; ++i) {
            qa[i] = (short)f2bf(bf2f((ushort_t)q0[i]) * C2);
            qb[i] = (short)f2bf(bf2f((ushort_t)q1[i]) * C2);
        }
    }

    const ushort_t* Kg = rK + (size_t)bh * 2048 * 32;   // row-major, 64B rows
    const ushort_t* Vg = vP + (size_t)bh * 32 * 2048;   // [d][n'] permuted

    // staging lanes: K chunk u=w*64+lane -> (rowK, gK); V chunk -> (dV, blkL, gL)
    const int uu   = w * 64 + lane;
    const int rowK = uu >> 2, gK = uu & 3;
    const int dV   = uu >> 4, blkL = (uu >> 2) & 3, gL = uu & 3;
    const ushort_t* srcK0 = Kg + (size_t)rowK * 32 + (gK ^ ((rowK >> 1) & 3)) * 8;
    const ushort_t* srcV0 = Vg + (size_t)dV * 2048 + ((blkL ^ (dV & 1)) * 32) + (gL ^ ((dV >> 1) & 3)) * 8;
    ushort_t* dstK = &smem[w * 512];            // +bufsel*8192; lane*16B appended by HW
    ushort_t* dstV = &smem[4096 + w * 512];

    // read-side swizzled offsets (constant per thread)
    const int gsw = g ^ ((l16 >> 1) & 3);
    const int kOffA = l16 * 32 + gsw * 8;            // + s*1024 (+512 for second frag)
    const int vOffA = l16 * 128 + gsw * 8;           // + blkV*32; +16*128 for second frag

    float ma = -1e30f, m8a = -1e30f, mb = -1e30f, m8b = -1e30f;
    f32x4 lva = {}, lvb = {};
    f32x4 aa0 = {}, aa1 = {}, ab0 = {}, ab1 = {};

    auto stage = [&](int t, int bufsel) {
        GLD_LDS16(srcK0 + (size_t)t * 128 * 32, dstK + bufsel * 8192);
        GLD_LDS16(srcV0 + (size_t)t * 4 * 32,  dstV + bufsel * 8192);
    };

    auto step = [&](int bufbase, int s) {
        const ushort_t* KB = &smem[bufbase];
        const ushort_t* VB = &smem[bufbase + 4096];
        short8 kf0 = *reinterpret_cast<const short8*>(&KB[s * 1024 + kOffA]);
        short8 kf1 = *reinterpret_cast<const short8*>(&KB[s * 1024 + 512 + kOffA]);
        const int blkV = s ^ (l16 & 1);
        short8 vf0 = *reinterpret_cast<const short8*>(&VB[vOffA + blkV * 32]);
        short8 vf1 = *reinterpret_cast<const short8*>(&VB[vOffA + 2048 + blkV * 32]);

        const f32x4 z4 = {};
        f32x4 sa0 = __builtin_amdgcn_mfma_f32_16x16x32_bf16(kf0, qa, z4, 0, 0, 0);
        f32x4 sa1 = __builtin_amdgcn_mfma_f32_16x16x32_bf16(kf1, qa, z4, 0, 0, 0);
        f32x4 sb0 = __builtin_amdgcn_mfma_f32_16x16x32_bf16(kf0, qb, z4, 0, 0, 0);
        f32x4 sb1 = __builtin_amdgcn_mfma_f32_16x16x32_bf16(kf1, qb, z4, 0, 0, 0);

        float pma = fmaxf(fmaxf(fmaxf(sa0[0], sa0[1]), fmaxf(sa0[2], sa0[3])),
                          fmaxf(fmaxf(sa1[0], sa1[1]), fmaxf(sa1[2], sa1[3])));
        float pmb = fmaxf(fmaxf(fmaxf(sb0[0], sb0[1]), fmaxf(sb0[2], sb0[3])),
                          fmaxf(fmaxf(sb1[0], sb1[1]), fmaxf(sb1[2], sb1[3])));

        if (!__all((pma <= m8a) && (pmb <= m8b))) {   // deferred-max trigger (rare)
            float ra = fmaxf(pma, __shfl_xor(pma, 16));
            ra = fmaxf(ra, __shfl_xor(ra, 32));
            float mna = fmaxf(ma, ra);
            float ala = __builtin_amdgcn_exp2f(ma - mna);
            lva *= ala; aa0 *= ala; aa1 *= ala;
            ma = mna; m8a = mna + 8.0f;

            float rb = fmaxf(pmb, __shfl_xor(pmb, 16));
            rb = fmaxf(rb, __shfl_xor(rb, 32));
            float mnb = fmaxf(mb, rb);
            float alb = __builtin_amdgcn_exp2f(mb - mnb);
            lvb *= alb; ab0 *= alb; ab1 *= alb;
            mb = mnb; m8b = mnb + 8.0f;
        }

        f32x4 pa0, pa1, pb0, pb1;
        #pragma unroll
        for (int r = 0; r < 4; ++r) {
            pa0[r] = __builtin_amdgcn_exp2f(sa0[r] - ma);
            pa1[r] = __builtin_amdgcn_exp2f(sa1[r] - ma);
            pb0[r] = __builtin_amdgcn_exp2f(sb0[r] - mb);
            pb1[r] = __builtin_amdgcn_exp2f(sb1[r] - mb);
        }
        lva += pa0; lva += pa1;
        lvb += pb0; lvb += pb1;

        short8 pfa, pfb;
        #pragma unroll
        for (int r = 0; r < 4; ++r) {
            pfa[r] = (short)f2bf_u(pa0[r]); pfa[4 + r] = (short)f2bf_u(pa1[r]);
            pfb[r] = (short)f2bf_u(pb0[r]); pfb[4 + r] = (short)f2bf_u(pb1[r]);
        }

        aa0 = __builtin_amdgcn_mfma_f32_16x16x32_bf16(vf0, pfa, aa0, 0, 0, 0);
        aa1 = __builtin_amdgcn_mfma_f32_16x16x32_bf16(vf1, pfa, aa1, 0, 0, 0);
        ab0 = __builtin_amdgcn_mfma_f32_16x16x32_bf16(vf0, pfb, ab0, 0, 0, 0);
        ab1 = __builtin_amdgcn_mfma_f32_16x16x32_bf16(vf1, pfb, ab1, 0, 0, 0);
    };

    // ---- 2-phase pipeline over 16 tiles of 128 kv ----
    stage(0, 0);
    __syncthreads();
    int cur = 0;
    for (int t = 0; t < 16; ++t) {
        if (t < 15) stage(t + 1, cur ^ 1);
        const int bufbase = cur * 8192;
        #pragma unroll
        for (int s = 0; s < 4; ++s) step(bufbase, s);
        __syncthreads();
        cur ^= 1;
    }

    // ---- epilogue ----
    float la = (lva[0] + lva[1]) + (lva[2] + lva[3]);
    la += __shfl_xor(la, 16); la += __shfl_xor(la, 32);
    float lb = (lvb[0] + lvb[1]) + (lvb[2] + lvb[3]);
    lb += __shfl_xor(lb, 16); lb += __shfl_xor(lb, 32);
    const float inva = 1.0f / la, invb = 1.0f / lb;

    ushort_t* orA = O + ((size_t)b * 2048 + qbase + l16) * 256 + h * 32;
    ushort_t* orB = O + ((size_t)b * 2048 + qbase + 16 + l16) * 256 + h * 32;
    ushort4 o0, o1;
    o0.x = f2bf(aa0[0] * inva); o0.y = f2bf(aa0[1] * inva);
    o0.z = f2bf(aa0[2] * inva); o0.w = f2bf(aa0[3] * inva);
    o1.x = f2bf(aa1[0] * inva); o1.y = f2bf(aa1[1] * inva);
    o1.z = f2bf(aa1[2] * inva); o1.w = f2bf(aa1[3] * inva);
    *reinterpret_cast<ushort4*>(orA + 4 * g) = o0;
    *reinterpret_cast<ushort4*>(orA + 16 + 4 * g) = o1;
    o0.x = f2bf(ab0[0] * invb); o0.y = f2bf(ab0[1] * invb);
    o0.z = f2bf(ab0[2] * invb); o0.w = f2bf(ab0[3] * invb);
    o1.x = f2bf(ab1[0] * invb); o1.y = f2bf(ab1[1] * invb);
    o1.z = f2bf(ab1[2] * invb); o1.w = f2bf(ab1[3] * invb);
    *reinterpret_cast<ushort4*>(orB + 4 * g) = o0;
    *reinterpret_cast<ushort4*>(orB + 16 + 4 * g) = o1;
}

// ---------- out-projection GEMM: C[4096 x 256] = A @ Bt^T + bias, f32 out ----------
__global__ __launch_bounds__(256) void gemm_out_kernel(
    const ushort_t* __restrict__ a0, const ushort_t* __restrict__ a1,
    const ushort_t* __restrict__ b0, const ushort_t* __restrict__ b1,
    float* __restrict__ c0, float* __restrict__ c1,
    const float* __restrict__ bias0, const float* __restrict__ bias1) {
    const ushort_t* A = blockIdx.z ? a1 : a0;
    const ushort_t* Bt = blockIdx.z ? b1 : b0;
    float* C = blockIdx.z ? c1 : c0;
    const float* bias = blockIdx.z ? bias1 : bias0;
    constexpr int K = 256, N = 256;
    const int w = threadIdx.x >> 6, lane = threadIdx.x & 63;
    const int l16 = lane & 15, g = lane >> 4;
    const int m0 = blockIdx.x * 64 + w * 16;
    const int cb = blockIdx.y * 64;

    f32x4 acc[4] = {};
    const ushort_t* Ap = A + (size_t)(m0 + l16) * K + 8 * g;
    const ushort_t* Bp = Bt + (size_t)(cb + l16) * K + 8 * g;
    #pragma unroll
    for (int ks = 0; ks < K; ks += 32) {
        short8 a = *reinterpret_cast<const short8*>(Ap + ks);
        #pragma unroll
        for (int c = 0; c < 4; ++c) {
            short8 b = *reinterpret_cast<const short8*>(Bp + (size_t)c * 16 * K + ks);
            acc[c] = __builtin_amdgcn_mfma_f32_16x16x32_bf16(a, b, acc[c], 0, 0, 0);
        }
    }
    #pragma unroll
    for (int c = 0; c < 4; ++c) {
        int col = cb + c * 16 + l16;
        #pragma unroll
        for (int r = 0; r < 4; ++r) {
            int row = m0 + 4 * g + r;
            C[(size_t)row * N + col] = acc[c][r] + bias[col];
        }
    }
}

// ---------- launch ----------
extern "C" void kernel_launch(void* const* d_in, const int* in_sizes, int n_in,
                              void* d_out, int out_size, void* d_ws, size_t ws_size,
                              hipStream_t stream) {
    const float* x_sed     = (const float*)d_in[0];
    const float* x_doa     = (const float*)d_in[1];
    const float* W_sed_in  = (const float*)d_in[2];
    const float* W_doa_in  = (const float*)d_in[3];
    const float* W_sed_out = (const float*)d_in[4];
    const float* b_sed_out = (const float*)d_in[5];
    const float* W_doa_out = (const float*)d_in[6];
    const float* b_doa_out = (const float*)d_in[7];
    float* out = (float*)d_out;

    ushort_t* ws = (ushort_t*)d_ws;
    ushort_t* wt_si  = ws;                          // 512*256
    ushort_t* wt_di  = wt_si  + 131072;             // 512*256
    ushort_t* wt_so  = wt_di  + 131072;             // 256*256
    ushort_t* wt_do  = wt_so  + 65536;              // 256*256
    ushort_t* rH_sed = wt_do  + 65536;              // 16*2048*32
    ushort_t* rH_doa = rH_sed + 1048576;
    ushort_t* vP_sed = rH_doa + 1048576;            // 16*32*2048 (permuted)
    ushort_t* vP_doa = vP_sed + 1048576;
    ushort_t* o_sed  = vP_doa + 1048576;            // 4096*256
    ushort_t* o_doa  = o_sed  + 1048576;
    // total ~13.3 MB of ws

    prep_w_kernel<<<dim3(512, 4), 256, 0, stream>>>(W_sed_in, W_doa_in, W_sed_out, W_doa_out,
                                                    wt_si, wt_di, wt_so, wt_do);
    gemm_in_kernel<<<dim3(64, 8, 2), 256, 0, stream>>>(x_sed, x_doa, wt_si, wt_di,
                                                       rH_sed, rH_doa, vP_sed, vP_doa);
    attn_kernel<<<dim3(256), 512, 0, stream>>>(rH_sed, rH_doa, vP_sed, vP_doa, o_sed, o_doa);
    gemm_out_kernel<<<dim3(64, 4, 2), 256, 0, stream>>>(o_sed, o_doa, wt_so, wt_do,
                                                        out, out + 1048576, b_sed_out, b_doa_out);
}

// Round 6
// 70.254 us; speedup vs baseline: 2.6923x; 1.1577x over previous
//
#include <hip/hip_runtime.h>
#include <hip/hip_bf16.h>

typedef short short8 __attribute__((ext_vector_type(8)));
typedef float f32x4 __attribute__((ext_vector_type(4)));
typedef float f32x16 __attribute__((ext_vector_type(16)));
typedef unsigned int uint4v __attribute__((ext_vector_type(4)));
typedef unsigned short ushort_t;

// ---------- bf16 helpers ----------
__device__ inline ushort_t f2bf(float f) {            // manual RNE
    union { float f; unsigned u; } x; x.f = f;
    unsigned r = x.u + 0x7fffu + ((x.u >> 16) & 1u);
    return (ushort_t)(r >> 16);
}
__device__ inline ushort_t f2bf_u(float x) {
    union { __hip_bfloat16 h; ushort_t u; } cv;
    cv.h = __float2bfloat16(x);
    return cv.u;
}
__device__ inline float bf2f(ushort_t u) {
    union { unsigned u; float f; } cv; cv.u = ((unsigned)u) << 16; return cv.f;
}

#define GLD_LDS16(src, dst)                                                  \
    __builtin_amdgcn_global_load_lds(                                        \
        (const __attribute__((address_space(1))) void*)(src),                \
        (__attribute__((address_space(3))) void*)(dst), 16, 0, 0)

// sqrt(SCALE * log2(e)); applied to r on both Q and K sides -> product = SCALE*log2(e)
#define RSQ 0.5050100f

// ---------- transpose + convert weights: Wt[j][k] = bf16(W[k][j]), K=256 rows ----------
__global__ __launch_bounds__(256) void prep_w_kernel(const float* __restrict__ w0,
                                                     const float* __restrict__ w1,
                                                     const float* __restrict__ w2,
                                                     const float* __restrict__ w3,
                                                     ushort_t* __restrict__ t0,
                                                     ushort_t* __restrict__ t1,
                                                     ushort_t* __restrict__ t2,
                                                     ushort_t* __restrict__ t3) {
    int z = blockIdx.y;
    const float* W; ushort_t* T; int J;
    if (z == 0)      { W = w0; T = t0; J = 512; }
    else if (z == 1) { W = w1; T = t1; J = 512; }
    else if (z == 2) { W = w2; T = t2; J = 256; }
    else             { W = w3; T = t3; J = 256; }
    int idx = blockIdx.x * 256 + threadIdx.x;   // idx = j*256 + k
    if (idx >= J * 256) return;
    int k = idx & 255, j = idx >> 8;
    T[idx] = f2bf(W[k * J + j]);
}

// ---------- in-projection GEMM (fused f32->bf16 convert of A) ----------
// Outputs (unit layouts, 16B units):
//  rU [bh][unit((n>>5),kh,(d>>3)&1,(n&31))][e=d&7]: element = bf16(r[n][d] * RSQ)
//     unit = ((n>>5)*4 + (d>>4)*2 + ((d>>3)&1))*32 + (n&31)
//  vU [bh][unit((n>>5),vh,hi,d)][e]: element = v^T[d][kv], kv-permuted so that
//     e <-> kv = (n>>5)*32 + vh*16 + 4*hi + (e&3) + 8*(e>>2)
__global__ __launch_bounds__(256) void gemm_in_kernel(
    const float* __restrict__ A0, const float* __restrict__ A1,
    const ushort_t* __restrict__ B0, const ushort_t* __restrict__ B1,
    ushort_t* __restrict__ R0, ushort_t* __restrict__ R1,
    ushort_t* __restrict__ V0, ushort_t* __restrict__ V1) {
    const float* A = blockIdx.z ? A1 : A0;
    const ushort_t* Bt = blockIdx.z ? B1 : B0;
    ushort_t* R = blockIdx.z ? R1 : R0;
    ushort_t* Vt = blockIdx.z ? V1 : V0;
    constexpr int K = 256;
    const int w = threadIdx.x >> 6, lane = threadIdx.x & 63;
    const int l16 = lane & 15, g = lane >> 4;
    const int m0 = blockIdx.x * 64 + w * 16;
    const int cb = blockIdx.y * 64;

    f32x4 acc[4] = {};
    const float* Ap = A + (size_t)(m0 + l16) * K + 8 * g;
    const ushort_t* Bp = Bt + (size_t)(cb + l16) * K + 8 * g;

    #pragma unroll
    for (int ks = 0; ks < K; ks += 32) {
        float4 af0 = *reinterpret_cast<const float4*>(Ap + ks);
        float4 af1 = *reinterpret_cast<const float4*>(Ap + ks + 4);
        short8 a;
        a[0] = (short)f2bf_u(af0.x); a[1] = (short)f2bf_u(af0.y);
        a[2] = (short)f2bf_u(af0.z); a[3] = (short)f2bf_u(af0.w);
        a[4] = (short)f2bf_u(af1.x); a[5] = (short)f2bf_u(af1.y);
        a[6] = (short)f2bf_u(af1.z); a[7] = (short)f2bf_u(af1.w);
        #pragma unroll
        for (int c = 0; c < 4; ++c) {
            short8 b = *reinterpret_cast<const short8*>(Bp + (size_t)c * 16 * K + ks);
            acc[c] = __builtin_amdgcn_mfma_f32_16x16x32_bf16(a, b, acc[c], 0, 0, 0);
        }
    }

    if (blockIdx.y < 4) {
        // r-part, unit layout, pre-scaled
        #pragma unroll
        for (int c = 0; c < 4; ++c) {
            int col = cb + c * 16 + l16;        // 0..255
            int h = col >> 5, d = col & 31;
            #pragma unroll
            for (int r = 0; r < 4; ++r) {
                int row = m0 + 4 * g + r;
                int bb = row >> 11, n = row & 2047;
                size_t base = (size_t)(bb * 8 + h) * 65536;
                int unit = ((n >> 5) * 4 + (d >> 4) * 2 + ((d >> 3) & 1)) * 32 + (n & 31);
                R[base + (size_t)unit * 8 + (d & 7)] = f2bf_u(acc[c][r] * RSQ);
            }
        }
    } else {
        // v-part, permuted unit layout; 4 consecutive n -> contiguous e run
        #pragma unroll
        for (int c = 0; c < 4; ++c) {
            int colp = cb - 256 + c * 16 + l16; // 0..255
            int h = colp >> 5, d = colp & 31;
            int row = m0 + 4 * g;
            int bb = row >> 11, n = row & 2047;
            size_t base = (size_t)(bb * 8 + h) * 65536;
            int nl = n & 31;
            int vh = nl >> 4, r4 = nl & 15;
            int hi2 = (r4 >> 2) & 1;
            int e0 = (r4 & 3) + 4 * (r4 >> 3);
            int unit = ((n >> 5) * 4 + vh * 2 + hi2) * 32 + d;
            ushort4 s;
            s.x = f2bf_u(acc[c][0]); s.y = f2bf_u(acc[c][1]);
            s.z = f2bf_u(acc[c][2]); s.w = f2bf_u(acc[c][3]);
            *reinterpret_cast<ushort4*>(Vt + base + (size_t)unit * 8 + e0) = s;
        }
    }
}

// ---------- flash attention: 32x32x16 MFMA, fixed-zero softmax reference point ----------
// 512 blocks (XCD-bijective): stream(dir,bh) x 8 qblk x 2 kv-halves. 8 waves/block,
// 32 q-rows/wave. K staged to LDS (linear 8KB copy, double-buffered); V read from
// global (coalesced dwordx4, L1-served since waves are tile-synchronized).
// Writes per-(kvhalf) partial acc (bf16) + l (f32); combined exactly in gemm_out.
__global__ __launch_bounds__(512, 4) void attn_kernel(
    const ushort_t* __restrict__ rU_sed, const ushort_t* __restrict__ rU_doa,
    const ushort_t* __restrict__ vU_sed, const ushort_t* __restrict__ vU_doa,
    ushort_t* __restrict__ part,   // [(stream*2+kvh)*2048 + q][32 d] bf16
    float* __restrict__ lpart) {   // [(stream*2+kvh)*2048 + q] f32
    __shared__ __align__(16) ushort_t smem[8192];   // 2 bufs x 8KB K-tile

    const int bid = blockIdx.x;                // 0..511
    const int xcd = bid & 7, i = bid >> 3;     // i 0..63
    const int stream = xcd * 4 + (i & 3);      // 0..31
    const int rest = i >> 2;                   // 0..15
    const int qblk = rest & 7, kvh = rest >> 3;
    const int dir = stream >> 4, bh = stream & 15;

    const ushort_t* rQ = dir ? rU_doa : rU_sed;
    const ushort_t* rK = dir ? rU_sed : rU_doa;
    const ushort_t* vV = dir ? vU_sed : vU_doa;

    const int tid = threadIdx.x;
    const int w = tid >> 6, lane = tid & 63;
    const int l31 = lane & 31, hi = lane >> 5;
    const size_t sB = (size_t)bh * 65536;
    const int qbase = qblk * 256 + w * 32;

    // Q B-frags (pre-scaled in gemm_in)
    const short8 qf0 = *reinterpret_cast<const short8*>(rQ + sB + (size_t)qbase * 32 + lane * 8);
    const short8 qf1 = *reinterpret_cast<const short8*>(rQ + sB + (size_t)qbase * 32 + 512 + lane * 8);

    const ushort_t* Kbase = rK + sB + (size_t)kvh * 32768;   // kvh*1024 kv * 32
    const ushort_t* Vbase = vV + sB + (size_t)kvh * 32768;
    const ushort_t* srcK = Kbase + tid * 8;                  // staging unit = tid
    const int dstK = w * 512;                                // ushort idx (wave-uniform)

    f32x16 acc = {};
    f32x4 lv = {};

    int buf = 0;
    GLD_LDS16(srcK, &smem[dstK]);
    __syncthreads();

    for (int t = 0; t < 8; ++t) {
        if (t < 7) GLD_LDS16(srcK + (size_t)(t + 1) * 4096, &smem[(buf ^ 1) * 4096 + dstK]);
        const ushort_t* KB = &smem[buf * 4096];
        const ushort_t* Vt = Vbase + (size_t)t * 4096;
        #pragma unroll
        for (int s = 0; s < 4; ++s) {
            short8 kf0 = *reinterpret_cast<const short8*>(KB + s * 1024 + lane * 8);
            short8 kf1 = *reinterpret_cast<const short8*>(KB + s * 1024 + 512 + lane * 8);
            short8 vf0 = *reinterpret_cast<const short8*>(Vt + s * 1024 + lane * 8);
            short8 vf1 = *reinterpret_cast<const short8*>(Vt + s * 1024 + 512 + lane * 8);

            f32x16 z16 = {};
            f32x16 st = __builtin_amdgcn_mfma_f32_32x32x16_bf16(kf0, qf0, z16, 0, 0, 0);
            st = __builtin_amdgcn_mfma_f32_32x32x16_bf16(kf1, qf1, st, 0, 0, 0);

            float p[16];
            #pragma unroll
            for (int j = 0; j < 16; ++j) {
                p[j] = __builtin_amdgcn_exp2f(st[j]);
            }
            #pragma unroll
            for (int j = 0; j < 16; ++j) lv[j & 3] += p[j];

            unsigned pk[8];
            #pragma unroll
            for (int j = 0; j < 8; ++j) {
                asm("v_cvt_pk_bf16_f32 %0, %1, %2" : "=v"(pk[j]) : "v"(p[2 * j]), "v"(p[2 * j + 1]));
            }
            union { uint4v u; short8 s; } c1, c2;
            c1.u = uint4v{pk[0], pk[1], pk[2], pk[3]};
            c2.u = uint4v{pk[4], pk[5], pk[6], pk[7]};

            acc = __builtin_amdgcn_mfma_f32_32x32x16_bf16(vf0, c1.s, acc, 0, 0, 0);
            acc = __builtin_amdgcn_mfma_f32_32x32x16_bf16(vf1, c2.s, acc, 0, 0, 0);
        }
        __syncthreads();
        buf ^= 1;
    }

    // epilogue: partial l and acc
    float l = (lv[0] + lv[1]) + (lv[2] + lv[3]);
    l += __shfl_xor(l, 32);
    const int q = qbase + l31;
    const size_t prow = ((size_t)stream * 2 + kvh) * 2048 + q;
    if (lane < 32) lpart[prow] = l;
    ushort_t* pa = part + prow * 32;
    #pragma unroll
    for (int r = 0; r < 16; ++r) {
        int d = (r & 3) + 8 * (r >> 2) + 4 * hi;
        pa[d] = f2bf(acc[r]);
    }
}

// ---------- out-projection GEMM with fused partial-combine ----------
// A[row][k] = (part0 + part1)(row, k) / (l0+l1), built on the fly per k-chunk.
__global__ __launch_bounds__(256) void gemm_out_kernel(
    const ushort_t* __restrict__ part, const float* __restrict__ lpart,
    const ushort_t* __restrict__ b0, const ushort_t* __restrict__ b1,
    float* __restrict__ c0, float* __restrict__ c1,
    const float* __restrict__ bias0, const float* __restrict__ bias1) {
    const int z = blockIdx.z;
    const ushort_t* Bt = z ? b1 : b0;
    float* C = z ? c1 : c0;
    const float* bias = z ? bias1 : bias0;
    constexpr int K = 256, N = 256;
    const int w = threadIdx.x >> 6, lane = threadIdx.x & 63;
    const int l16 = lane & 15, g = lane >> 4;
    const int m0 = blockIdx.x * 64 + w * 16;
    const int cb = blockIdx.y * 64;

    const int row = m0 + l16;
    const int bb = row >> 11, q = row & 2047;

    f32x4 acc[4] = {};
    const ushort_t* Bp = Bt + (size_t)(cb + l16) * K + 8 * g;
    #pragma unroll
    for (int it = 0; it < 8; ++it) {           // it = head h, k-chunk base = it*32
        const int strm = z * 16 + bb * 8 + it;
        const size_t pr0 = ((size_t)strm * 2) * 2048 + q;
        float l0 = lpart[pr0], l1 = lpart[pr0 + 2048];
        float inv = 1.0f / (l0 + l1);
        const ushort_t* p0 = part + pr0 * 32 + 8 * g;
        const ushort_t* p1 = p0 + (size_t)2048 * 32;
        short8 pa = *reinterpret_cast<const short8*>(p0);
        short8 pb = *reinterpret_cast<const short8*>(p1);
        short8 a;
        #pragma unroll
        for (int e = 0; e < 8; ++e) {
            a[e] = (short)f2bf_u((bf2f((ushort_t)pa[e]) + bf2f((ushort_t)pb[e])) * inv);
        }
        #pragma unroll
        for (int c = 0; c < 4; ++c) {
            short8 b = *reinterpret_cast<const short8*>(Bp + (size_t)c * 16 * K + it * 32);
            acc[c] = __builtin_amdgcn_mfma_f32_16x16x32_bf16(a, b, acc[c], 0, 0, 0);
        }
    }
    #pragma unroll
    for (int c = 0; c < 4; ++c) {
        int col = cb + c * 16 + l16;
        #pragma unroll
        for (int r = 0; r < 4; ++r) {
            int orow = m0 + 4 * g + r;
            C[(size_t)orow * N + col] = acc[c][r] + bias[col];
        }
    }
}

// ---------- launch ----------
extern "C" void kernel_launch(void* const* d_in, const int* in_sizes, int n_in,
                              void* d_out, int out_size, void* d_ws, size_t ws_size,
                              hipStream_t stream) {
    const float* x_sed     = (const float*)d_in[0];
    const float* x_doa     = (const float*)d_in[1];
    const float* W_sed_in  = (const float*)d_in[2];
    const float* W_doa_in  = (const float*)d_in[3];
    const float* W_sed_out = (const float*)d_in[4];
    const float* b_sed_out = (const float*)d_in[5];
    const float* W_doa_out = (const float*)d_in[6];
    const float* b_doa_out = (const float*)d_in[7];
    float* out = (float*)d_out;

    ushort_t* ws = (ushort_t*)d_ws;
    ushort_t* wt_si  = ws;                          // 512*256
    ushort_t* wt_di  = wt_si  + 131072;             // 512*256
    ushort_t* wt_so  = wt_di  + 131072;             // 256*256
    ushort_t* wt_do  = wt_so  + 65536;              // 256*256
    ushort_t* rU_sed = wt_do  + 65536;              // 16*65536 (unit layout)
    ushort_t* rU_doa = rU_sed + 1048576;
    ushort_t* vU_sed = rU_doa + 1048576;            // 16*65536 (permuted unit layout)
    ushort_t* vU_doa = vU_sed + 1048576;
    ushort_t* part   = vU_doa + 1048576;            // 2*16*2*2048*32 bf16 = 8MB
    float*    lpart  = (float*)(part + 4194304);    // 2*16*2*2048 f32
    // total ~18.1 MB of ws

    prep_w_kernel<<<dim3(512, 4), 256, 0, stream>>>(W_sed_in, W_doa_in, W_sed_out, W_doa_out,
                                                    wt_si, wt_di, wt_so, wt_do);
    gemm_in_kernel<<<dim3(64, 8, 2), 256, 0, stream>>>(x_sed, x_doa, wt_si, wt_di,
                                                       rU_sed, rU_doa, vU_sed, vU_doa);
    attn_kernel<<<dim3(512), 512, 0, stream>>>(rU_sed, rU_doa, vU_sed, vU_doa, part, lpart);
    gemm_out_kernel<<<dim3(64, 4, 2), 256, 0, stream>>>(part, lpart, wt_so, wt_do,
                                                        out, out + 1048576, b_sed_out, b_doa_out);
}

// Round 7
// 67.770 us; speedup vs baseline: 2.7910x; 1.0367x over previous
//
#include <hip/hip_runtime.h>
#include <hip/hip_bf16.h>

typedef short short8 __attribute__((ext_vector_type(8)));
typedef float f32x4 __attribute__((ext_vector_type(4)));
typedef float f32x16 __attribute__((ext_vector_type(16)));
typedef unsigned int uint4v __attribute__((ext_vector_type(4)));
typedef unsigned short ushort_t;

// ---------- bf16 helpers ----------
__device__ inline ushort_t f2bf(float f) {            // manual RNE
    union { float f; unsigned u; } x; x.f = f;
    unsigned r = x.u + 0x7fffu + ((x.u >> 16) & 1u);
    return (ushort_t)(r >> 16);
}
__device__ inline ushort_t f2bf_u(float x) {
    union { __hip_bfloat16 h; ushort_t u; } cv;
    cv.h = __float2bfloat16(x);
    return cv.u;
}
__device__ inline float bf2f(ushort_t u) {
    union { unsigned u; float f; } cv; cv.u = ((unsigned)u) << 16; return cv.f;
}

#define GLD_LDS16(src, dst)                                                  \
    __builtin_amdgcn_global_load_lds(                                        \
        (const __attribute__((address_space(1))) void*)(src),                \
        (__attribute__((address_space(3))) void*)(dst), 16, 0, 0)

// sqrt(SCALE * log2(e)); applied to r on both Q and K sides -> product = SCALE*log2(e)
#define RSQ 0.5050100f

// ---------- transpose + convert weights (coalesced, LDS tile) ----------
// Wt[j][k] = bf16(W[k][j]); W is [256][J], Wt is [J][256].
__global__ __launch_bounds__(256) void prep_w_kernel(const float* __restrict__ w0,
                                                     const float* __restrict__ w1,
                                                     const float* __restrict__ w2,
                                                     const float* __restrict__ w3,
                                                     ushort_t* __restrict__ t0,
                                                     ushort_t* __restrict__ t1,
                                                     ushort_t* __restrict__ t2,
                                                     ushort_t* __restrict__ t3) {
    __shared__ float tile[64][65];
    int z = blockIdx.y;
    const float* W; ushort_t* T; int J;
    if (z == 0)      { W = w0; T = t0; J = 512; }
    else if (z == 1) { W = w1; T = t1; J = 512; }
    else if (z == 2) { W = w2; T = t2; J = 256; }
    else             { W = w3; T = t3; J = 256; }
    int ntj = J >> 6;
    int nt = ntj * 4;                      // (J/64) * (256/64)
    int tix = blockIdx.x;
    if (tix >= nt) return;
    int tj = tix % ntj, tk = tix / ntj;
    int j0 = tj * 64, k0 = tk * 64;
    int tid = threadIdx.x;

    int jj = (tid & 15) * 4, kk0 = tid >> 4;
    #pragma unroll
    for (int kk = kk0; kk < 64; kk += 16) {
        float4 v = *reinterpret_cast<const float4*>(&W[(size_t)(k0 + kk) * J + j0 + jj]);
        tile[kk][jj] = v.x; tile[kk][jj + 1] = v.y;
        tile[kk][jj + 2] = v.z; tile[kk][jj + 3] = v.w;
    }
    __syncthreads();
    int kk4 = (tid & 15) * 4, jj0 = tid >> 4;
    #pragma unroll
    for (int j2 = jj0; j2 < 64; j2 += 16) {
        ushort4 o;
        o.x = f2bf(tile[kk4][j2]);     o.y = f2bf(tile[kk4 + 1][j2]);
        o.z = f2bf(tile[kk4 + 2][j2]); o.w = f2bf(tile[kk4 + 3][j2]);
        *reinterpret_cast<ushort4*>(&T[(size_t)(j0 + j2) * 256 + k0 + kk4]) = o;
    }
}

// ---------- in-projection GEMM (fused f32->bf16 convert of A), 128-col tiles ----------
// Outputs (unit layouts, 16B units):
//  rU [bh][unit((n>>5),kh,(d>>3)&1,(n&31))][e=d&7]: element = bf16(r[n][d] * RSQ)
//  vU [bh][unit((n>>5),vh,hi,d)][e]: element = v^T[d][kv], kv-permuted so that
//     e <-> kv = (n>>5)*32 + vh*16 + 4*hi + (e&3) + 8*(e>>2)
__global__ __launch_bounds__(256) void gemm_in_kernel(
    const float* __restrict__ A0, const float* __restrict__ A1,
    const ushort_t* __restrict__ B0, const ushort_t* __restrict__ B1,
    ushort_t* __restrict__ R0, ushort_t* __restrict__ R1,
    ushort_t* __restrict__ V0, ushort_t* __restrict__ V1) {
    const float* A = blockIdx.z ? A1 : A0;
    const ushort_t* Bt = blockIdx.z ? B1 : B0;
    ushort_t* R = blockIdx.z ? R1 : R0;
    ushort_t* Vt = blockIdx.z ? V1 : V0;
    constexpr int K = 256;
    const int w = threadIdx.x >> 6, lane = threadIdx.x & 63;
    const int l16 = lane & 15, g = lane >> 4;
    const int m0 = blockIdx.x * 64 + w * 16;
    const int cb = blockIdx.y * 128;

    f32x4 acc[8] = {};
    const float* Ap = A + (size_t)(m0 + l16) * K + 8 * g;
    const ushort_t* Bp = Bt + (size_t)(cb + l16) * K + 8 * g;

    #pragma unroll
    for (int ks = 0; ks < K; ks += 32) {
        float4 af0 = *reinterpret_cast<const float4*>(Ap + ks);
        float4 af1 = *reinterpret_cast<const float4*>(Ap + ks + 4);
        short8 a;
        a[0] = (short)f2bf_u(af0.x); a[1] = (short)f2bf_u(af0.y);
        a[2] = (short)f2bf_u(af0.z); a[3] = (short)f2bf_u(af0.w);
        a[4] = (short)f2bf_u(af1.x); a[5] = (short)f2bf_u(af1.y);
        a[6] = (short)f2bf_u(af1.z); a[7] = (short)f2bf_u(af1.w);
        #pragma unroll
        for (int c = 0; c < 8; ++c) {
            short8 b = *reinterpret_cast<const short8*>(Bp + (size_t)c * 16 * K + ks);
            acc[c] = __builtin_amdgcn_mfma_f32_16x16x32_bf16(a, b, acc[c], 0, 0, 0);
        }
    }

    if (blockIdx.y < 2) {
        // r-part, unit layout, pre-scaled
        #pragma unroll
        for (int c = 0; c < 8; ++c) {
            int col = cb + c * 16 + l16;        // 0..255
            int h = col >> 5, d = col & 31;
            #pragma unroll
            for (int r = 0; r < 4; ++r) {
                int row = m0 + 4 * g + r;
                int bb = row >> 11, n = row & 2047;
                size_t base = (size_t)(bb * 8 + h) * 65536;
                int unit = ((n >> 5) * 4 + (d >> 4) * 2 + ((d >> 3) & 1)) * 32 + (n & 31);
                R[base + (size_t)unit * 8 + (d & 7)] = f2bf_u(acc[c][r] * RSQ);
            }
        }
    } else {
        // v-part, permuted unit layout; 4 consecutive n -> contiguous e run
        #pragma unroll
        for (int c = 0; c < 8; ++c) {
            int colp = cb - 256 + c * 16 + l16; // 0..255
            int h = colp >> 5, d = colp & 31;
            int row = m0 + 4 * g;
            int bb = row >> 11, n = row & 2047;
            size_t base = (size_t)(bb * 8 + h) * 65536;
            int nl = n & 31;
            int vh = nl >> 4, r4 = nl & 15;
            int hi2 = (r4 >> 2) & 1;
            int e0 = (r4 & 3) + 4 * (r4 >> 3);
            int unit = ((n >> 5) * 4 + vh * 2 + hi2) * 32 + d;
            ushort4 s;
            s.x = f2bf_u(acc[c][0]); s.y = f2bf_u(acc[c][1]);
            s.z = f2bf_u(acc[c][2]); s.w = f2bf_u(acc[c][3]);
            *reinterpret_cast<ushort4*>(Vt + base + (size_t)unit * 8 + e0) = s;
        }
    }
}

// ---------- flash attention: 32x32x16 MFMA, K AND V LDS-staged, 2-phase ----------
// 512 blocks (XCD-bijective): stream(dir,bh) x 8 qblk x 2 kv-halves. 8 waves/block,
// 32 q-rows/wave. Per 128-kv tile: 2 global_load_lds per wave (K 8KB + V 8KB),
// double-buffered; 4 compute steps; one __syncthreads per tile.
// Writes per-(kvhalf) partial acc (bf16) + l (f32); combined exactly in gemm_out.
__global__ __launch_bounds__(512, 4) void attn_kernel(
    const ushort_t* __restrict__ rU_sed, const ushort_t* __restrict__ rU_doa,
    const ushort_t* __restrict__ vU_sed, const ushort_t* __restrict__ vU_doa,
    ushort_t* __restrict__ part,   // [(stream*2+kvh)*2048 + q][32 d] bf16
    float* __restrict__ lpart) {   // [(stream*2+kvh)*2048 + q] f32
    __shared__ __align__(16) ushort_t smem[16384];   // 2 bufs x (K 8KB | V 8KB)

    const int bid = blockIdx.x;                // 0..511
    const int xcd = bid & 7, i = bid >> 3;     // i 0..63
    const int stream = xcd * 4 + (i & 3);      // 0..31
    const int rest = i >> 2;                   // 0..15
    const int qblk = rest & 7, kvh = rest >> 3;
    const int dir = stream >> 4, bh = stream & 15;

    const ushort_t* rQ = dir ? rU_doa : rU_sed;
    const ushort_t* rK = dir ? rU_sed : rU_doa;
    const ushort_t* vV = dir ? vU_sed : vU_doa;

    const int tid = threadIdx.x;
    const int w = tid >> 6, lane = tid & 63;
    const int l31 = lane & 31, hi = lane >> 5;
    const size_t sB = (size_t)bh * 65536;
    const int qbase = qblk * 256 + w * 32;

    // Q B-frags (pre-scaled in gemm_in)
    const short8 qf0 = *reinterpret_cast<const short8*>(rQ + sB + (size_t)qbase * 32 + lane * 8);
    const short8 qf1 = *reinterpret_cast<const short8*>(rQ + sB + (size_t)qbase * 32 + 512 + lane * 8);

    const ushort_t* Kbase = rK + sB + (size_t)kvh * 32768;   // kvh*1024 kv * 32
    const ushort_t* Vbase = vV + sB + (size_t)kvh * 32768;
    const ushort_t* srcK = Kbase + tid * 8;                  // per-lane global source
    const ushort_t* srcV = Vbase + tid * 8;
    const int dstK = w * 512;                                // wave-uniform LDS base
    const int dstV = 4096 + w * 512;

    f32x16 acc = {};
    f32x4 lv = {};

    auto stage = [&](int t, int bufsel) {
        GLD_LDS16(srcK + (size_t)t * 4096, &smem[bufsel * 8192 + dstK]);
        GLD_LDS16(srcV + (size_t)t * 4096, &smem[bufsel * 8192 + dstV]);
    };

    int buf = 0;
    stage(0, 0);
    __syncthreads();

    for (int t = 0; t < 8; ++t) {
        if (t < 7) stage(t + 1, buf ^ 1);
        const ushort_t* KB = &smem[buf * 8192];
        const ushort_t* VB = &smem[buf * 8192 + 4096];
        #pragma unroll
        for (int s = 0; s < 4; ++s) {
            short8 kf0 = *reinterpret_cast<const short8*>(KB + s * 1024 + lane * 8);
            short8 kf1 = *reinterpret_cast<const short8*>(KB + s * 1024 + 512 + lane * 8);
            short8 vf0 = *reinterpret_cast<const short8*>(VB + s * 1024 + lane * 8);
            short8 vf1 = *reinterpret_cast<const short8*>(VB + s * 1024 + 512 + lane * 8);

            f32x16 z16 = {};
            f32x16 st = __builtin_amdgcn_mfma_f32_32x32x16_bf16(kf0, qf0, z16, 0, 0, 0);
            st = __builtin_amdgcn_mfma_f32_32x32x16_bf16(kf1, qf1, st, 0, 0, 0);

            float p[16];
            #pragma unroll
            for (int j = 0; j < 16; ++j) {
                p[j] = __builtin_amdgcn_exp2f(st[j]);
            }
            #pragma unroll
            for (int j = 0; j < 16; ++j) lv[j & 3] += p[j];

            unsigned pk[8];
            #pragma unroll
            for (int j = 0; j < 8; ++j) {
                asm("v_cvt_pk_bf16_f32 %0, %1, %2" : "=v"(pk[j]) : "v"(p[2 * j]), "v"(p[2 * j + 1]));
            }
            union { uint4v u; short8 s; } c1, c2;
            c1.u = uint4v{pk[0], pk[1], pk[2], pk[3]};
            c2.u = uint4v{pk[4], pk[5], pk[6], pk[7]};

            acc = __builtin_amdgcn_mfma_f32_32x32x16_bf16(vf0, c1.s, acc, 0, 0, 0);
            acc = __builtin_amdgcn_mfma_f32_32x32x16_bf16(vf1, c2.s, acc, 0, 0, 0);
        }
        __syncthreads();
        buf ^= 1;
    }

    // epilogue: partial l and acc
    float l = (lv[0] + lv[1]) + (lv[2] + lv[3]);
    l += __shfl_xor(l, 32);
    const int q = qbase + l31;
    const size_t prow = ((size_t)stream * 2 + kvh) * 2048 + q;
    if (lane < 32) lpart[prow] = l;
    ushort_t* pa = part + prow * 32;
    #pragma unroll
    for (int r = 0; r < 16; ++r) {
        int d = (r & 3) + 8 * (r >> 2) + 4 * hi;
        pa[d] = f2bf(acc[r]);
    }
}

// ---------- out-projection GEMM with fused partial-combine, 128-col tiles ----------
// A[row][k] = (part0 + part1)(row, k) / (l0+l1), built on the fly per k-chunk.
__global__ __launch_bounds__(256) void gemm_out_kernel(
    const ushort_t* __restrict__ part, const float* __restrict__ lpart,
    const ushort_t* __restrict__ b0, const ushort_t* __restrict__ b1,
    float* __restrict__ c0, float* __restrict__ c1,
    const float* __restrict__ bias0, const float* __restrict__ bias1) {
    const int z = blockIdx.z;
    const ushort_t* Bt = z ? b1 : b0;
    float* C = z ? c1 : c0;
    const float* bias = z ? bias1 : bias0;
    constexpr int K = 256, N = 256;
    const int w = threadIdx.x >> 6, lane = threadIdx.x & 63;
    const int l16 = lane & 15, g = lane >> 4;
    const int m0 = blockIdx.x * 64 + w * 16;
    const int cb = blockIdx.y * 128;

    const int row = m0 + l16;
    const int bb = row >> 11, q = row & 2047;

    f32x4 acc[8] = {};
    const ushort_t* Bp = Bt + (size_t)(cb + l16) * K + 8 * g;
    #pragma unroll
    for (int it = 0; it < 8; ++it) {           // it = head h, k-chunk base = it*32
        const int strm = z * 16 + bb * 8 + it;
        const size_t pr0 = ((size_t)strm * 2) * 2048 + q;
        float l0 = lpart[pr0], l1 = lpart[pr0 + 2048];
        float inv = 1.0f / (l0 + l1);
        const ushort_t* p0 = part + pr0 * 32 + 8 * g;
        const ushort_t* p1 = p0 + (size_t)2048 * 32;
        short8 pa = *reinterpret_cast<const short8*>(p0);
        short8 pb = *reinterpret_cast<const short8*>(p1);
        short8 a;
        #pragma unroll
        for (int e = 0; e < 8; ++e) {
            a[e] = (short)f2bf_u((bf2f((ushort_t)pa[e]) + bf2f((ushort_t)pb[e])) * inv);
        }
        #pragma unroll
        for (int c = 0; c < 8; ++c) {
            short8 b = *reinterpret_cast<const short8*>(Bp + (size_t)c * 16 * K + it * 32);
            acc[c] = __builtin_amdgcn_mfma_f32_16x16x32_bf16(a, b, acc[c], 0, 0, 0);
        }
    }
    #pragma unroll
    for (int c = 0; c < 8; ++c) {
        int col = cb + c * 16 + l16;
        #pragma unroll
        for (int r = 0; r < 4; ++r) {
            int orow = m0 + 4 * g + r;
            C[(size_t)orow * N + col] = acc[c][r] + bias[col];
        }
    }
}

// ---------- launch ----------
extern "C" void kernel_launch(void* const* d_in, const int* in_sizes, int n_in,
                              void* d_out, int out_size, void* d_ws, size_t ws_size,
                              hipStream_t stream) {
    const float* x_sed     = (const float*)d_in[0];
    const float* x_doa     = (const float*)d_in[1];
    const float* W_sed_in  = (const float*)d_in[2];
    const float* W_doa_in  = (const float*)d_in[3];
    const float* W_sed_out = (const float*)d_in[4];
    const float* b_sed_out = (const float*)d_in[5];
    const float* W_doa_out = (const float*)d_in[6];
    const float* b_doa_out = (const float*)d_in[7];
    float* out = (float*)d_out;

    ushort_t* ws = (ushort_t*)d_ws;
    ushort_t* wt_si  = ws;                          // 512*256
    ushort_t* wt_di  = wt_si  + 131072;             // 512*256
    ushort_t* wt_so  = wt_di  + 131072;             // 256*256
    ushort_t* wt_do  = wt_so  + 65536;              // 256*256
    ushort_t* rU_sed = wt_do  + 65536;              // 16*65536 (unit layout)
    ushort_t* rU_doa = rU_sed + 1048576;
    ushort_t* vU_sed = rU_doa + 1048576;            // 16*65536 (permuted unit layout)
    ushort_t* vU_doa = vU_sed + 1048576;
    ushort_t* part   = vU_doa + 1048576;            // 2*16*2*2048*32 bf16 = 8MB
    float*    lpart  = (float*)(part + 4194304);    // 2*16*2*2048 f32
    // total ~18.1 MB of ws

    prep_w_kernel<<<dim3(32, 4), 256, 0, stream>>>(W_sed_in, W_doa_in, W_sed_out, W_doa_out,
                                                   wt_si, wt_di, wt_so, wt_do);
    gemm_in_kernel<<<dim3(64, 4, 2), 256, 0, stream>>>(x_sed, x_doa, wt_si, wt_di,
                                                       rU_sed, rU_doa, vU_sed, vU_doa);
    attn_kernel<<<dim3(512), 512, 0, stream>>>(rU_sed, rU_doa, vU_sed, vU_doa, part, lpart);
    gemm_out_kernel<<<dim3(64, 2, 2), 256, 0, stream>>>(part, lpart, wt_so, wt_do,
                                                        out, out + 1048576, b_sed_out, b_doa_out);
}